// Round 1
// baseline (501.205 us; speedup 1.0000x reference)
//
#include <hip/hip_runtime.h>

typedef __bf16 bf16;
typedef __bf16 bf16x8 __attribute__((ext_vector_type(8)));
typedef float  f32x4  __attribute__((ext_vector_type(4)));

#define S 512
#define DD 768
#define LL 64
#define BB 4
#define NKT 12   // 768 / 64

__device__ __forceinline__ void async_copy16(const void* g, void* l) {
    __builtin_amdgcn_global_load_lds(
        (const __attribute__((address_space(1))) unsigned int*)g,
        (__attribute__((address_space(3))) unsigned int*)l,
        16, 0, 0);
}

__device__ __forceinline__ bf16x8 scale_cvt(float4 a, float4 b, float4 ua, float4 ub) {
    bf16x8 p;
    p[0] = (bf16)(a.x * ua.x); p[1] = (bf16)(a.y * ua.y);
    p[2] = (bf16)(a.z * ua.z); p[3] = (bf16)(a.w * ua.w);
    p[4] = (bf16)(b.x * ub.x); p[5] = (bf16)(b.y * ub.y);
    p[6] = (bf16)(b.z * ub.z); p[7] = (bf16)(b.w * ub.w);
    return p;
}

// ---------------- prepass 1: dep fp32 -> bf16 ----------------
__global__ void cvt_dep_kernel(const float* __restrict__ dep, bf16* __restrict__ out) {
    int idx = (blockIdx.x * 256 + threadIdx.x) * 8;
    float4 a = *(const float4*)(dep + idx);
    float4 c = *(const float4*)(dep + idx + 4);
    bf16x8 p;
    p[0] = (bf16)a.x; p[1] = (bf16)a.y; p[2] = (bf16)a.z; p[3] = (bf16)a.w;
    p[4] = (bf16)c.x; p[5] = (bf16)c.y; p[6] = (bf16)c.z; p[7] = (bf16)c.w;
    *(bf16x8*)(out + idx) = p;
}

// ---------------- prepass 2: t2h[b,l,i], t2d'[b,l,o] (+bias) ----------------
__global__ void t2_kernel(const float* __restrict__ head, const float* __restrict__ dep,
                          const float* __restrict__ W, const float* __restrict__ bias,
                          float* __restrict__ t2h, float* __restrict__ t2d) {
    __shared__ float Wl[16][DD];
    __shared__ float red[64][4][16];
    int bid = blockIdx.x;
    int sel = bid >> 7;
    int r   = bid & 127;
    int b   = r >> 5;
    int lg  = (r >> 3) & 3;
    int ic  = r & 7;
    const float* src = sel ? dep : head;
    int t = threadIdx.x;

    for (int l16 = 0; l16 < 16; ++l16) {
        const float* wp = W + (size_t)(lg * 16 + l16) * (2 * DD) + sel * DD;
        Wl[l16][t]       = wp[t];
        Wl[l16][t + 256] = wp[t + 256];
        Wl[l16][t + 512] = wp[t + 512];
    }
    __syncthreads();

    int iq = t >> 2, dq = t & 3;
    int i  = ic * 64 + iq;
    const float* rowp = src + (size_t)(b * S + i) * DD;
    float acc[16];
#pragma unroll
    for (int l16 = 0; l16 < 16; ++l16) acc[l16] = 0.f;
    for (int it = 0; it < 48; ++it) {
        int d = dq * 4 + it * 16;
        float4 x = *(const float4*)(rowp + d);
#pragma unroll
        for (int l16 = 0; l16 < 16; ++l16) {
            float4 wv = *(const float4*)&Wl[l16][d];
            acc[l16] += x.x * wv.x + x.y * wv.y + x.z * wv.z + x.w * wv.w;
        }
    }
#pragma unroll
    for (int l16 = 0; l16 < 16; ++l16) red[iq][dq][l16] = acc[l16];
    __syncthreads();

    int iq2 = t >> 2, l4 = t & 3;
    float* dst = sel ? t2d : t2h;
#pragma unroll
    for (int j = 0; j < 4; ++j) {
        int l16 = l4 * 4 + j;
        float v = red[iq2][0][l16] + red[iq2][1][l16] + red[iq2][2][l16] + red[iq2][3][l16];
        if (sel) v += bias[lg * 16 + l16];
        dst[(size_t)(b * LL + lg * 16 + l16) * S + ic * 64 + iq2] = v;
    }
}

// ---------------- main: 256x256 tile, BK=64, 8 waves, 4-phase K-tile pipeline ----------------
template<int MH>
__device__ __forceinline__ void load_a(bf16x8 (&aF)[8], const bf16* Ac, int offA0, int offA1) {
#pragma unroll
    for (int mi = 0; mi < 4; ++mi) {
        aF[mi * 2 + 0] = *(const bf16x8*)(Ac + offA0 + (MH * 4 + mi) * 1024);
        aF[mi * 2 + 1] = *(const bf16x8*)(Ac + offA1 + (MH * 4 + mi) * 1024);
    }
}

template<int NH>
__device__ __forceinline__ void load_b(bf16x8 (&bFr)[8], const bf16* Bc, int offB0, int offB1) {
#pragma unroll
    for (int ni = 0; ni < 2; ++ni) {
        bFr[(NH * 2 + ni) * 2 + 0] = *(const bf16x8*)(Bc + offB0 + (NH * 2 + ni) * 1024);
        bFr[(NH * 2 + ni) * 2 + 1] = *(const bf16x8*)(Bc + offB1 + (NH * 2 + ni) * 1024);
    }
}

template<int MH, int NH>
__device__ __forceinline__ void do_mfma(f32x4 (&acc)[8][4], const bf16x8 (&aF)[8], const bf16x8 (&bFr)[8]) {
#pragma unroll
    for (int mi = 0; mi < 4; ++mi)
#pragma unroll
        for (int ni = 0; ni < 2; ++ni)
#pragma unroll
            for (int ks = 0; ks < 2; ++ks)
                acc[MH * 4 + mi][NH * 2 + ni] = __builtin_amdgcn_mfma_f32_16x16x32_bf16(
                    aF[mi * 2 + ks], bFr[(NH * 2 + ni) * 2 + ks],
                    acc[MH * 4 + mi][NH * 2 + ni], 0, 0, 0);
}

#define PHASE_BEGIN() do { __builtin_amdgcn_s_barrier(); \
    asm volatile("s_waitcnt lgkmcnt(0)" ::: "memory"); \
    __builtin_amdgcn_s_setprio(1); } while (0)
#define PHASE_END() do { __builtin_amdgcn_s_setprio(0); \
    __builtin_amdgcn_s_barrier(); } while (0)

__global__ __launch_bounds__(512, 2) void biaffine_main(
    const float* __restrict__ head, const bf16* __restrict__ depb,
    const float* __restrict__ U, const float* __restrict__ t2h,
    const float* __restrict__ t2d, float* __restrict__ out) {
    __shared__ __align__(16) bf16 As[2][256][64];
    __shared__ __align__(16) bf16 Bs[2][256][64];
    __shared__ __align__(16) float Ulds[DD];

    const int tid  = threadIdx.x;
    const int lane = tid & 63;
    const int w    = tid >> 6;
    const int bi0  = (blockIdx.x & 1) << 8;
    const int bo0  = (blockIdx.x >> 1) << 8;
    const int l    = blockIdx.y;
    const int b    = blockIdx.z;

    bf16* AsB = &As[0][0][0];
    bf16* BsB = &Bs[0][0][0];

    // ---- U staging (768 f32) ----
    Ulds[tid] = U[(size_t)l * DD + tid];
    if (tid < DD - 512) Ulds[512 + tid] = U[(size_t)l * DD + 512 + tid];

    // ---- A staging layout: thread -> (row, colhalf); swizzle chunk ^= row&7 ----
    const int arow = tid >> 1;
    const int ach  = tid & 1;
    const float* hp = head + (size_t)(b * S + bi0 + arow) * DD + ach * 32;
    const int as7 = arow & 7;
    const int wr0 = arow * 64 + (((ach * 4 + 0) ^ as7) * 8);
    const int wr1 = arow * 64 + (((ach * 4 + 1) ^ as7) * 8);
    const int wr2 = arow * 64 + (((ach * 4 + 2) ^ as7) * 8);
    const int wr3 = arow * 64 + (((ach * 4 + 3) ^ as7) * 8);

    // ---- B staging via global_load_lds: linear LDS dest, pre-swizzled global src ----
    const int brg = lane >> 3;     // row within 8-row wave group
    const int bsl = lane & 7;      // chunk slot
    const bf16* bsrc0 = depb + (size_t)(b * S + bo0 +   0 + w * 8 + brg) * DD + ((bsl ^ brg) * 8);
    const bf16* bsrc1 = depb + (size_t)(b * S + bo0 +  64 + w * 8 + brg) * DD + ((bsl ^ brg) * 8);
    const bf16* bsrc2 = depb + (size_t)(b * S + bo0 + 128 + w * 8 + brg) * DD + ((bsl ^ brg) * 8);
    const bf16* bsrc3 = depb + (size_t)(b * S + bo0 + 192 + w * 8 + brg) * DD + ((bsl ^ brg) * 8);
    bf16* BwB0 = &Bs[0][  0 + w * 8][0];
    bf16* BwB1 = &Bs[0][ 64 + w * 8][0];
    bf16* BwB2 = &Bs[0][128 + w * 8][0];
    bf16* BwB3 = &Bs[0][192 + w * 8][0];

    // ---- fragment read offsets (elements), swizzled ----
    const int wr = w & 1, wc = w >> 1;
    const int mrow = lane & 15, q = lane >> 4;
    const int sw = mrow & 7;
    const int offA0 = (wr * 128 + mrow) * 64 + ((q ^ sw) * 8);
    const int offA1 = (wr * 128 + mrow) * 64 + (((4 + q) ^ sw) * 8);
    const int offB0 = (wc * 64 + mrow) * 64 + ((q ^ sw) * 8);
    const int offB1 = (wc * 64 + mrow) * 64 + (((4 + q) ^ sw) * 8);

    f32x4 acc[8][4];
#pragma unroll
    for (int mi = 0; mi < 8; ++mi)
#pragma unroll
        for (int ni = 0; ni < 4; ++ni)
            acc[mi][ni] = (f32x4){0.f, 0.f, 0.f, 0.f};

    bf16x8 aF[8], bFr[8];
    float4 aLd0, aLd1, aLd2, aLd3, aLd4, aLd5, aLd6, aLd7;

    // ---- prologue: stage K-tile 0 into buffer 0 ----
    aLd0 = *(const float4*)(hp +  0); aLd1 = *(const float4*)(hp +  4);
    aLd2 = *(const float4*)(hp +  8); aLd3 = *(const float4*)(hp + 12);
    aLd4 = *(const float4*)(hp + 16); aLd5 = *(const float4*)(hp + 20);
    aLd6 = *(const float4*)(hp + 24); aLd7 = *(const float4*)(hp + 28);
    async_copy16(bsrc0, BwB0);
    async_copy16(bsrc1, BwB1);
    async_copy16(bsrc2, BwB2);
    async_copy16(bsrc3, BwB3);
    __syncthreads();               // Ulds visible (also drains prologue loads)
    {
        const float* up = &Ulds[ach * 32];
        bf16* Aw = AsB;
        float4 u0, u1; bf16x8 pk;
        u0 = *(const float4*)(up +  0); u1 = *(const float4*)(up +  4);
        pk = scale_cvt(aLd0, aLd1, u0, u1); *(bf16x8*)(Aw + wr0) = pk;
        u0 = *(const float4*)(up +  8); u1 = *(const float4*)(up + 12);
        pk = scale_cvt(aLd2, aLd3, u0, u1); *(bf16x8*)(Aw + wr1) = pk;
        u0 = *(const float4*)(up + 16); u1 = *(const float4*)(up + 20);
        pk = scale_cvt(aLd4, aLd5, u0, u1); *(bf16x8*)(Aw + wr2) = pk;
        u0 = *(const float4*)(up + 24); u1 = *(const float4*)(up + 28);
        pk = scale_cvt(aLd6, aLd7, u0, u1); *(bf16x8*)(Aw + wr3) = pk;
    }
    __syncthreads();               // tile 0 fully staged

    // ---- main loop: tile kt computes from buf (kt&1), stages kt+1 into buf (kt&1)^1 ----
#pragma unroll 2
    for (int kt = 0; kt < NKT; ++kt) {
        const int c = kt & 1;
        const int s = c ^ 1;
        const bool st = (kt < NKT - 1);
        const int kt1 = kt + 1;
        const bf16* Ac = AsB + c * 16384;
        const bf16* Bc = BsB + c * 16384;
        bf16* Aw = AsB + s * 16384;
        const float* hpt = hp + kt1 * 64;

        // P0: read A m-half0 + B n-half0; issue A grp1 + B gld 0,1
        load_a<0>(aF, Ac, offA0, offA1);
        load_b<0>(bFr, Bc, offB0, offB1);
        if (st) {
            aLd0 = *(const float4*)(hpt +  0); aLd1 = *(const float4*)(hpt +  4);
            aLd2 = *(const float4*)(hpt +  8); aLd3 = *(const float4*)(hpt + 12);
            async_copy16(bsrc0 + kt1 * 64, BwB0 + s * 16384);
            async_copy16(bsrc1 + kt1 * 64, BwB1 + s * 16384);
        }
        PHASE_BEGIN(); do_mfma<0, 0>(acc, aF, bFr); PHASE_END();

        // P1: read B n-half1; issue A grp2 + B gld 2,3
        load_b<1>(bFr, Bc, offB0, offB1);
        if (st) {
            aLd4 = *(const float4*)(hpt + 16); aLd5 = *(const float4*)(hpt + 20);
            aLd6 = *(const float4*)(hpt + 24); aLd7 = *(const float4*)(hpt + 28);
            async_copy16(bsrc2 + kt1 * 64, BwB2 + s * 16384);
            async_copy16(bsrc3 + kt1 * 64, BwB3 + s * 16384);
        }
        PHASE_BEGIN(); do_mfma<0, 1>(acc, aF, bFr); PHASE_END();

        // P2: read A m-half1; scale + write A (compiler inserts vmcnt waits for aLd)
        load_a<1>(aF, Ac, offA0, offA1);
        if (st) {
            const float* up = &Ulds[kt1 * 64 + ach * 32];
            float4 u0, u1; bf16x8 pk;
            u0 = *(const float4*)(up +  0); u1 = *(const float4*)(up +  4);
            pk = scale_cvt(aLd0, aLd1, u0, u1); *(bf16x8*)(Aw + wr0) = pk;
            u0 = *(const float4*)(up +  8); u1 = *(const float4*)(up + 12);
            pk = scale_cvt(aLd2, aLd3, u0, u1); *(bf16x8*)(Aw + wr1) = pk;
            u0 = *(const float4*)(up + 16); u1 = *(const float4*)(up + 20);
            pk = scale_cvt(aLd4, aLd5, u0, u1); *(bf16x8*)(Aw + wr2) = pk;
            u0 = *(const float4*)(up + 24); u1 = *(const float4*)(up + 28);
            pk = scale_cvt(aLd6, aLd7, u0, u1); *(bf16x8*)(Aw + wr3) = pk;
        }
        PHASE_BEGIN(); do_mfma<1, 1>(acc, aF, bFr); PHASE_END();

        // P3: drain B gload_lds for next tile (issued >=2 phases ago)
        if (st) asm volatile("s_waitcnt vmcnt(0)" ::: "memory");
        PHASE_BEGIN(); do_mfma<1, 0>(acc, aF, bFr); PHASE_END();
    }

    // ---- epilogue: + t2h[row] + t2d'[col], store ----
    const size_t bl = (size_t)(b * LL + l);
    const float* t2hp = t2h + bl * S + bi0 + wr * 128;
    const float* t2dp = t2d + bl * S + bo0 + wc * 64;
    float* outbase = out + bl * (size_t)(S * S);
#pragma unroll
    for (int mi = 0; mi < 8; ++mi) {
        float4 th = *(const float4*)&t2hp[mi * 16 + q * 4];
        int row0 = bi0 + wr * 128 + mi * 16 + q * 4;
#pragma unroll
        for (int ni = 0; ni < 4; ++ni) {
            int col = bo0 + wc * 64 + ni * 16 + mrow;
            float td = t2dp[ni * 16 + mrow];
            float* op = outbase + (size_t)row0 * S + col;
            op[0 * S] = acc[mi][ni][0] + th.x + td;
            op[1 * S] = acc[mi][ni][1] + th.y + td;
            op[2 * S] = acc[mi][ni][2] + th.z + td;
            op[3 * S] = acc[mi][ni][3] + th.w + td;
        }
    }
}

extern "C" void kernel_launch(void* const* d_in, const int* in_sizes, int n_in,
                              void* d_out, int out_size, void* d_ws, size_t ws_size,
                              hipStream_t stream) {
    const float* head = (const float*)d_in[0];
    const float* dep  = (const float*)d_in[1];
    const float* U    = (const float*)d_in[2];
    const float* W    = (const float*)d_in[3];
    const float* bias = (const float*)d_in[4];
    float* out = (float*)d_out;

    char*  ws   = (char*)d_ws;
    bf16*  depb = (bf16*)ws;                               // B*S*D*2   = 3,145,728 B
    float* t2h  = (float*)(ws + 3145728);                  // B*L*S*4   =   524,288 B
    float* t2d  = (float*)(ws + 3145728 + 524288);         // B*L*S*4   =   524,288 B

    cvt_dep_kernel<<<768, 256, 0, stream>>>(dep, depb);
    t2_kernel<<<256, 256, 0, stream>>>(head, dep, W, bias, t2h, t2d);
    biaffine_main<<<dim3(4, LL, BB), 512, 0, stream>>>(head, depb, U, t2h, t2d, out);
}

// Round 2
// 389.363 us; speedup vs baseline: 1.2872x; 1.2872x over previous
//
#include <hip/hip_runtime.h>

typedef __bf16 bf16;
typedef __bf16 bf16x8 __attribute__((ext_vector_type(8)));
typedef float  f32x4  __attribute__((ext_vector_type(4)));

#define S 512
#define DD 768
#define LL 64
#define BB 4

__device__ __forceinline__ void async_copy16(const void* g, void* l) {
    __builtin_amdgcn_global_load_lds(
        (const __attribute__((address_space(1))) unsigned int*)g,
        (__attribute__((address_space(3))) unsigned int*)l,
        16, 0, 0);
}

__device__ __forceinline__ bf16x8 scale_cvt(float4 a, float4 b, float4 ua, float4 ub) {
    bf16x8 p;
    p[0] = (bf16)(a.x * ua.x); p[1] = (bf16)(a.y * ua.y);
    p[2] = (bf16)(a.z * ua.z); p[3] = (bf16)(a.w * ua.w);
    p[4] = (bf16)(b.x * ub.x); p[5] = (bf16)(b.y * ub.y);
    p[6] = (bf16)(b.z * ub.z); p[7] = (bf16)(b.w * ub.w);
    return p;
}

// ---------------- prepass 1: dep fp32 -> bf16 ----------------
__global__ void cvt_dep_kernel(const float* __restrict__ dep, bf16* __restrict__ out) {
    int idx = (blockIdx.x * 256 + threadIdx.x) * 8;
    float4 a = *(const float4*)(dep + idx);
    float4 c = *(const float4*)(dep + idx + 4);
    bf16x8 p;
    p[0] = (bf16)a.x; p[1] = (bf16)a.y; p[2] = (bf16)a.z; p[3] = (bf16)a.w;
    p[4] = (bf16)c.x; p[5] = (bf16)c.y; p[6] = (bf16)c.z; p[7] = (bf16)c.w;
    *(bf16x8*)(out + idx) = p;
}

// ---------------- prepass 2: t2h[b,l,i], t2d'[b,l,o] (+bias) ----------------
__global__ void t2_kernel(const float* __restrict__ head, const float* __restrict__ dep,
                          const float* __restrict__ W, const float* __restrict__ bias,
                          float* __restrict__ t2h, float* __restrict__ t2d) {
    __shared__ float Wl[16][DD];
    __shared__ float red[64][4][16];
    int bid = blockIdx.x;
    int sel = bid >> 7;
    int r   = bid & 127;
    int b   = r >> 5;
    int lg  = (r >> 3) & 3;
    int ic  = r & 7;
    const float* src = sel ? dep : head;
    int t = threadIdx.x;

    for (int l16 = 0; l16 < 16; ++l16) {
        const float* wp = W + (size_t)(lg * 16 + l16) * (2 * DD) + sel * DD;
        Wl[l16][t]       = wp[t];
        Wl[l16][t + 256] = wp[t + 256];
        Wl[l16][t + 512] = wp[t + 512];
    }
    __syncthreads();

    int iq = t >> 2, dq = t & 3;
    int i  = ic * 64 + iq;
    const float* rowp = src + (size_t)(b * S + i) * DD;
    float acc[16];
#pragma unroll
    for (int l16 = 0; l16 < 16; ++l16) acc[l16] = 0.f;
    for (int it = 0; it < 48; ++it) {
        int d = dq * 4 + it * 16;
        float4 x = *(const float4*)(rowp + d);
#pragma unroll
        for (int l16 = 0; l16 < 16; ++l16) {
            float4 wv = *(const float4*)&Wl[l16][d];
            acc[l16] += x.x * wv.x + x.y * wv.y + x.z * wv.z + x.w * wv.w;
        }
    }
#pragma unroll
    for (int l16 = 0; l16 < 16; ++l16) red[iq][dq][l16] = acc[l16];
    __syncthreads();

    int iq2 = t >> 2, l4 = t & 3;
    float* dst = sel ? t2d : t2h;
#pragma unroll
    for (int j = 0; j < 4; ++j) {
        int l16 = l4 * 4 + j;
        float v = red[iq2][0][l16] + red[iq2][1][l16] + red[iq2][2][l16] + red[iq2][3][l16];
        if (sel) v += bias[lg * 16 + l16];
        dst[(size_t)(b * LL + lg * 16 + l16) * S + ic * 64 + iq2] = v;
    }
}

// ---------------- main: 128x128 tile, BK=32, 4 waves, double-buffered, 1 sync/K-step ----------------
// Round-0 structure (2-3 blocks/CU of TLP) + dbuf prefetch: loads for kt+1 issued before
// kt's MFMA, scale/write after, single __syncthreads() drain per step (full-step latency cover).
__global__ __launch_bounds__(256, 3) void biaffine_main(
    const float* __restrict__ head, const bf16* __restrict__ depb,
    const float* __restrict__ U, const float* __restrict__ t2h,
    const float* __restrict__ t2d, float* __restrict__ out) {
    __shared__ __align__(16) bf16 As[2][128][32];
    __shared__ __align__(16) bf16 Bs[2][128][32];
    __shared__ __align__(16) float Ulds[DD];

    const int tid  = threadIdx.x;
    const int lane = tid & 63;
    const int w    = tid >> 6;
    const int bi0  = (blockIdx.x & 3) << 7;
    const int bo0  = (blockIdx.x >> 2) << 7;
    const int l    = blockIdx.y;
    const int b    = blockIdx.z;

    bf16* AsB = &As[0][0][0];
    bf16* BsB = &Bs[0][0][0];

    {   // stage U[l] (768 f32)
        const float* up = U + (size_t)l * DD;
        Ulds[tid]       = up[tid];
        Ulds[tid + 256] = up[tid + 256];
        Ulds[tid + 512] = up[tid + 512];
    }

    // A staging: thread handles rows r1 and r1+64; phys slot cp holds data chunk ca = cp^sw
    const int r1 = tid >> 2;
    const int cp = tid & 3;
    const int sw = (r1 >> 1) & 3;          // same for r1 and r1+64
    const int ca = cp ^ sw;
    const float* hp0 = head + (size_t)(b * S + bi0 + r1) * DD + ca * 8;
    const float* hp1 = hp0 + (size_t)64 * DD;
    const int aoff0 = r1 * 32 + cp * 8;
    const int aoff1 = (r1 + 64) * 32 + cp * 8;

    // B staging via global_load_lds: 2 insts/wave, 16 rows each, swizzle in global addr
    const int rB0 = w * 32 + (lane >> 2);
    const int rB1 = rB0 + 16;
    const int cpB = lane & 3;
    const bf16* bg0 = depb + (size_t)(b * S + bo0 + rB0) * DD + (cpB ^ ((rB0 >> 1) & 3)) * 8;
    const bf16* bg1 = depb + (size_t)(b * S + bo0 + rB1) * DD + (cpB ^ ((rB1 >> 1) & 3)) * 8;
    const int boff0 = (w * 32) * 32;       // wave-uniform LDS element offsets
    const int boff1 = (w * 32 + 16) * 32;

    // fragment element offsets (constant across K loop)
    const int wr = w & 1, wc = w >> 1;
    const int mrow = lane & 15, q = lane >> 4;
    int aFo[4], bFo[4];
#pragma unroll
    for (int mi = 0; mi < 4; ++mi) {
        int rowA = wr * 64 + mi * 16 + mrow;
        aFo[mi] = rowA * 32 + ((q ^ ((rowA >> 1) & 3)) * 8);
        int rowB = wc * 64 + mi * 16 + mrow;
        bFo[mi] = rowB * 32 + ((q ^ ((rowB >> 1) & 3)) * 8);
    }

    f32x4 acc[4][4];
#pragma unroll
    for (int mi = 0; mi < 4; ++mi)
#pragma unroll
        for (int ni = 0; ni < 4; ++ni)
            acc[mi][ni] = (f32x4){0.f, 0.f, 0.f, 0.f};

    // ---- prologue: stage K-step 0 into buffer 0 ----
    float4 h0a = *(const float4*)(hp0);
    float4 h0b = *(const float4*)(hp0 + 4);
    float4 h1a = *(const float4*)(hp1);
    float4 h1b = *(const float4*)(hp1 + 4);
    async_copy16(bg0, BsB + boff0);
    async_copy16(bg1, BsB + boff1);
    __syncthreads();               // Ulds visible, prologue glds drained
    {
        const float* uu = &Ulds[ca * 8];
        float4 ua = *(const float4*)(uu);
        float4 ub = *(const float4*)(uu + 4);
        *(bf16x8*)(AsB + aoff0) = scale_cvt(h0a, h0b, ua, ub);
        *(bf16x8*)(AsB + aoff1) = scale_cvt(h1a, h1b, ua, ub);
    }
    __syncthreads();               // K-step 0 fully staged

    // ---- main loop: compute buf (kt&1), stage kt+1 into the other ----
    for (int kt = 0; kt < 24; ++kt) {
        const int coff = (kt & 1) * 4096;
        const int soff = coff ^ 4096;
        const bool st = kt < 23;

        if (st) {   // issue next-step global loads FIRST (full-step latency cover)
            const float* h0 = hp0 + (kt + 1) * 32;
            const float* h1 = hp1 + (kt + 1) * 32;
            h0a = *(const float4*)(h0);
            h0b = *(const float4*)(h0 + 4);
            h1a = *(const float4*)(h1);
            h1b = *(const float4*)(h1 + 4);
            async_copy16(bg0 + (kt + 1) * 32, BsB + soff + boff0);
            async_copy16(bg1 + (kt + 1) * 32, BsB + soff + boff1);
        }

        bf16x8 af[4], bfr[4];
#pragma unroll
        for (int mi = 0; mi < 4; ++mi) af[mi]  = *(const bf16x8*)(AsB + coff + aFo[mi]);
#pragma unroll
        for (int ni = 0; ni < 4; ++ni) bfr[ni] = *(const bf16x8*)(BsB + coff + bFo[ni]);
#pragma unroll
        for (int mi = 0; mi < 4; ++mi)
#pragma unroll
            for (int ni = 0; ni < 4; ++ni)
                acc[mi][ni] = __builtin_amdgcn_mfma_f32_16x16x32_bf16(af[mi], bfr[ni], acc[mi][ni], 0, 0, 0);

        if (st) {   // scale + write A for kt+1 (compiler vmcnt-waits here, loads had MFMA cover)
            const float* uu = &Ulds[(kt + 1) * 32 + ca * 8];
            float4 ua = *(const float4*)(uu);
            float4 ub = *(const float4*)(uu + 4);
            *(bf16x8*)(AsB + soff + aoff0) = scale_cvt(h0a, h0b, ua, ub);
            *(bf16x8*)(AsB + soff + aoff1) = scale_cvt(h1a, h1b, ua, ub);
        }
        __syncthreads();           // one drain+publish per K-step
    }

    // ---- epilogue: + t2h[row] + t2d'[col] ----
    const size_t bl = (size_t)(b * LL + l);
    const float* t2hp = t2h + bl * S + bi0 + wr * 64;
    const float* t2dp = t2d + bl * S + bo0 + wc * 64;
    float* outbase = out + bl * (size_t)(S * S);
#pragma unroll
    for (int mi = 0; mi < 4; ++mi) {
        float4 th = *(const float4*)&t2hp[mi * 16 + q * 4];
        int row0 = bi0 + wr * 64 + mi * 16 + q * 4;
#pragma unroll
        for (int ni = 0; ni < 4; ++ni) {
            int col = bo0 + wc * 64 + ni * 16 + mrow;
            float td = t2dp[ni * 16 + mrow];
            float* op = outbase + (size_t)row0 * S + col;
            op[0 * S] = acc[mi][ni][0] + th.x + td;
            op[1 * S] = acc[mi][ni][1] + th.y + td;
            op[2 * S] = acc[mi][ni][2] + th.z + td;
            op[3 * S] = acc[mi][ni][3] + th.w + td;
        }
    }
}

extern "C" void kernel_launch(void* const* d_in, const int* in_sizes, int n_in,
                              void* d_out, int out_size, void* d_ws, size_t ws_size,
                              hipStream_t stream) {
    const float* head = (const float*)d_in[0];
    const float* dep  = (const float*)d_in[1];
    const float* U    = (const float*)d_in[2];
    const float* W    = (const float*)d_in[3];
    const float* bias = (const float*)d_in[4];
    float* out = (float*)d_out;

    char*  ws   = (char*)d_ws;
    bf16*  depb = (bf16*)ws;                               // B*S*D*2   = 3,145,728 B
    float* t2h  = (float*)(ws + 3145728);                  // B*L*S*4   =   524,288 B
    float* t2d  = (float*)(ws + 3145728 + 524288);         // B*L*S*4   =   524,288 B

    cvt_dep_kernel<<<768, 256, 0, stream>>>(dep, depb);
    t2_kernel<<<256, 256, 0, stream>>>(head, dep, W, bias, t2h, t2d);
    biaffine_main<<<dim3(16, LL, BB), 256, 0, stream>>>(head, depb, U, t2h, t2d, out);
}